// Round 8
// baseline (163.759 us; speedup 1.0000x reference)
//
#include <hip/hip_runtime.h>
#include <hip/hip_bf16.h>
#include <stdint.h>

// LSTM cell as one fused bf16 MFMA GEMM:
//   gates(8192 x 4096) = A(8192 x 2048) @ Bp(4096 x 2048)^T, fused LSTM epilogue.
//
// ROUND 8: LDS-traffic cut. Old structure moved 192KB/K-tile/CU through the
// LDS read port (2304cy) vs 2060cy of MFMA -> LDS was the binding pipe.
// Change: B never touches LDS. pack_B emits B in per-lane MFMA fragment order
// ([bn*4+wn][kt][kk][nn][lane]x16B), GEMM loads B frags global->VGPR (1KB/wave
// coalesced, L2-resident stream). A is reg-staged (plain global loads +
// swizzled ds_write) into a double-buffered 32KBx2 LDS. Everything is
// compiler-dataflow-tracked -> no manual vmcnt; ONE __syncthreads per K-tile;
// intra-tile phases free-run so ds_read/MFMA/VMEM overlap per-wave.
// LDS budget now 1920cy < MFMA 2060cy.
//
// B-reg stagger to fit VGPR: cur-kk0 loaded one tile ahead (ping/pong
// Bk0A/Bk0B), cur-kk1 loaded at own tile top (single Bk1, used 2 quadrants
// later ~500cy cover). A(T+1) loaded at T top, ds_written into buf^1 mid/late
// tile (buf^1 readers finished before T's opening barrier -> race-free with
// the single end-of-tile barrier).

#define B_DIM 8192
#define I_DIM 1024
#define H_DIM 1024
#define K_DIM 2048   // I + H
#define N_DIM 4096   // 4 gates * H
#define NKT   32     // K_DIM / 64

typedef short bf16x8 __attribute__((ext_vector_type(8)));
typedef float f32x4 __attribute__((ext_vector_type(4)));

__device__ __forceinline__ unsigned short f2bf(float f) {
  unsigned int u = __float_as_uint(f);
  u += 0x7FFFu + ((u >> 16) & 1u);   // RNE
  return (unsigned short)(u >> 16);
}

// ---- merged pack: A = [x|h] -> bf16 row-major (B_DIM,K_DIM);
//      B -> bf16 fragment-order [bn*4+wn][kt 32][kk 2][nn 4][lane 64] x 16B ----
__global__ void pack_AB_kernel(const float* __restrict__ x, const float* __restrict__ h,
                               const float* __restrict__ Wxi, const float* __restrict__ Whi,
                               const float* __restrict__ Wxf, const float* __restrict__ Whf,
                               const float* __restrict__ Wxc, const float* __restrict__ Whc,
                               const float* __restrict__ Wxo, const float* __restrict__ Who,
                               unsigned short* __restrict__ outA,
                               unsigned short* __restrict__ outB) {
  const int totalA = B_DIM * K_DIM / 8;             // 2M 16B-units
  const int total  = totalA + N_DIM * K_DIM / 8;    // +1M
  for (int idx = blockIdx.x * blockDim.x + threadIdx.x; idx < total;
       idx += gridDim.x * blockDim.x) {
    const float* src;
    unsigned short* dst;
    if (idx < totalA) {
      int row = idx >> 8;              // K_DIM/8 = 256 units/row
      int col = (idx & 255) * 8;
      src = (col < I_DIM) ? (x + (size_t)row * I_DIM + col)
                          : (h + (size_t)row * H_DIM + (col - I_DIM));
      dst = outA + (size_t)idx * 8;
    } else {
      int u2 = idx - totalA;
      int lane_ = u2 & 63, nn = (u2 >> 6) & 3, kk = (u2 >> 8) & 1;
      int kt = (u2 >> 9) & 31, wn = (u2 >> 14) & 3, bn = u2 >> 16;
      int r = bn * 256 + wn * 64 + nn * 16 + (lane_ & 15);   // packed B row (C col)
      int k = kt * 64 + kk * 32 + (lane_ >> 4) * 8;
      int g = (r >> 4) & 3;
      int hh = ((r >> 6) << 4) | (r & 15);
      src = (k < I_DIM)
          ? ((g == 0 ? Wxi : g == 1 ? Wxf : g == 2 ? Wxc : Wxo) + (size_t)hh * I_DIM + k)
          : ((g == 0 ? Whi : g == 1 ? Whf : g == 2 ? Whc : Who) + (size_t)hh * H_DIM + (k - I_DIM));
      dst = outB + (size_t)u2 * 8;
    }
    const float4* s4 = (const float4*)src;
    float4 v0 = s4[0], v1 = s4[1];
    bf16x8 o;
    o[0] = f2bf(v0.x); o[1] = f2bf(v0.y); o[2] = f2bf(v0.z); o[3] = f2bf(v0.w);
    o[4] = f2bf(v1.x); o[5] = f2bf(v1.y); o[6] = f2bf(v1.z); o[7] = f2bf(v1.w);
    *(bf16x8*)dst = o;
  }
}

// ---- GEMM 256x256 tile, BK=64, 8 waves (2Mx4N), A-only LDS dbuf 64KB ----

// quadrant (MH, k-half): 4 A ds_reads + 16 independent MFMA
#define QUAD(MH, KOFF, BR) do {                                               \
    bf16x8 aq[4];                                                             \
    _Pragma("unroll") for (int mf = 0; mf < 4; ++mf)                          \
      aq[mf] = *(const bf16x8*)(ldsAr + _bo + (MH)*8192 + mf * 2048 + (KOFF));\
    __builtin_amdgcn_s_setprio(1);                                            \
    _Pragma("unroll") for (int mf = 0; mf < 4; ++mf)                          \
    _Pragma("unroll") for (int nn = 0; nn < 4; ++nn)                          \
      acc[(MH)*4 + mf][nn] = __builtin_amdgcn_mfma_f32_16x16x32_bf16(         \
          aq[mf], BR[nn], acc[(MH)*4 + mf][nn], 0, 0, 0);                     \
    __builtin_amdgcn_s_setprio(0);                                            \
  } while (0)

#define KTILE(BUF, KT, BC0, BN0) do {                                         \
    const int _bo  = (BUF) * 32768;                                           \
    const int _bo1 = ((BUF) ^ 1) * 32768;                                     \
    int _kt1 = (KT) + 1 < NKT ? (KT) + 1 : NKT - 1;                           \
    const unsigned short* _ga = gAst + (size_t)_kt1 * 64;                     \
    bf16x8 ar0 = *(const bf16x8*)(_ga);                                       \
    bf16x8 ar1 = *(const bf16x8*)(_ga + 8);                                   \
    bf16x8 ar2 = *(const bf16x8*)(_ga + 16);                                  \
    bf16x8 ar3 = *(const bf16x8*)(_ga + 24);                                  \
    _Pragma("unroll") for (int nn = 0; nn < 4; ++nn)                          \
      Bk1[nn] = *(const bf16x8*)(gBfr + (size_t)(KT) * 4096 + 2048 + nn*512); \
    _Pragma("unroll") for (int nn = 0; nn < 4; ++nn)                          \
      BN0[nn] = *(const bf16x8*)(gBfr + (size_t)_kt1 * 4096 + nn * 512);      \
    QUAD(0, rd0, BC0);                                                        \
    QUAD(1, rd0, BC0);                                                        \
    *(bf16x8*)(ldsAw + _bo1 + woff0) = ar0;                                   \
    *(bf16x8*)(ldsAw + _bo1 + woff1) = ar1;                                   \
    QUAD(0, rd1, Bk1);                                                        \
    QUAD(1, rd1, Bk1);                                                        \
    *(bf16x8*)(ldsAw + _bo1 + woff2) = ar2;                                   \
    *(bf16x8*)(ldsAw + _bo1 + woff3) = ar3;                                   \
    __syncthreads();                                                          \
  } while (0)

__launch_bounds__(512, 2)
__global__ void lstm_gemm_kernel(const unsigned short* __restrict__ A,
                                 const unsigned short* __restrict__ Bp,
                                 const float* __restrict__ c_prev,
                                 const float* __restrict__ bxi, const float* __restrict__ bhi,
                                 const float* __restrict__ bxf, const float* __restrict__ bhf,
                                 const float* __restrict__ bxc, const float* __restrict__ bhc,
                                 const float* __restrict__ bxo, const float* __restrict__ bho,
                                 float* __restrict__ out) {
  __shared__ __align__(16) char lds[65536];   // A only: 2 bufs x 256x64 bf16

  // XCD-aware bijective swizzle (512 % 8 == 0)
  const int nwg = gridDim.x;
  int bid = blockIdx.x;
  int q = nwg >> 3;
  int wg = (bid & 7) * q + (bid >> 3);
  int bm = wg >> 4;          // 32 M-tiles
  int bn = wg & 15;          // 16 N-tiles

  int tid = threadIdx.x;
  int lane = tid & 63;
  int wid = tid >> 6;        // 8 waves
  int wm = wid >> 2;         // 2 M-wave rows (128 rows each)
  int wn = wid & 3;          // 4 N-wave cols (64 cols each)

  // ---- A reg-staging addresses: thread t owns row t>>1, 64B half (t&1) ----
  const unsigned short* gAst = A + (size_t)(bm * 256 + (tid >> 1)) * K_DIM + (tid & 1) * 32;
  char* ldsAw = lds + (tid >> 1) * 128;
  // swizzled write chunk offsets: chunk c at phys (c ^ (row&7))*16
  int wr7 = (tid >> 1) & 7;
  int woff0 = ((((tid & 1) * 4 + 0) ^ wr7) << 4);
  int woff1 = ((((tid & 1) * 4 + 1) ^ wr7) << 4);
  int woff2 = ((((tid & 1) * 4 + 2) ^ wr7) << 4);
  int woff3 = ((((tid & 1) * 4 + 3) ^ wr7) << 4);

  // ---- B fragment stream (global->reg): [bn*4+wn][kt][kk][nn][lane]x8bf16 ----
  const unsigned short* gBfr = Bp + (size_t)(bn * 4 + wn) * 131072 + lane * 8;

  // ---- A LDS read bases; frag row&7 == lane&7 ----
  int c15 = lane & 15;
  int kl = lane >> 4;                   // k-group 0..3
  const char* ldsAr = lds + wm * 16384 + c15 * 128;
  int rd0 = ((kl) ^ (lane & 7)) << 4;         // kk=0 chunk
  int rd1 = ((4 | kl) ^ (lane & 7)) << 4;     // kk=1 chunk

  f32x4 acc[8][4];
  f32x4 zero = {0.f, 0.f, 0.f, 0.f};
#pragma unroll
  for (int m = 0; m < 8; ++m)
#pragma unroll
    for (int n = 0; n < 4; ++n) acc[m][n] = zero;

  bf16x8 Bk0A[4], Bk0B[4], Bk1[4];

  // ---- prologue: B(0) kk0 + A(0) -> buf0 ----
#pragma unroll
  for (int nn = 0; nn < 4; ++nn)
    Bk0A[nn] = *(const bf16x8*)(gBfr + nn * 512);
  {
    bf16x8 a0 = *(const bf16x8*)(gAst);
    bf16x8 a1 = *(const bf16x8*)(gAst + 8);
    bf16x8 a2 = *(const bf16x8*)(gAst + 16);
    bf16x8 a3 = *(const bf16x8*)(gAst + 24);
    *(bf16x8*)(ldsAw + woff0) = a0;
    *(bf16x8*)(ldsAw + woff1) = a1;
    *(bf16x8*)(ldsAw + woff2) = a2;
    *(bf16x8*)(ldsAw + woff3) = a3;
  }
  __syncthreads();

#pragma unroll 1
  for (int kt = 0; kt < NKT; kt += 2) {
    KTILE(0, kt, Bk0A, Bk0B);
    KTILE(1, kt + 1, Bk0B, Bk0A);
  }

  // ---- fused LSTM epilogue: lane owns hidden unit h; acc[mi][g][j] = gate g ----
  int h = (bn * 4 + wn) * 16 + c15;
  float bi = bxi[h] + bhi[h];
  float bf_ = bxf[h] + bhf[h];
  float bc = bxc[h] + bhc[h];
  float bo = bxo[h] + bho[h];
  int row0 = bm * 256 + wm * 128 + kl * 4;
#pragma unroll
  for (int mi = 0; mi < 8; ++mi) {
#pragma unroll
    for (int j = 0; j < 4; ++j) {
      int r = row0 + mi * 16 + j;
      size_t off = (size_t)r * H_DIM + h;
      float zi = acc[mi][0][j] + bi;
      float zf = acc[mi][1][j] + bf_;
      float zc = acc[mi][2][j] + bc;
      float zo = acc[mi][3][j] + bo;
      float ig = 1.f / (1.f + __expf(-zi));
      float fg = 1.f / (1.f + __expf(-zf));
      float e2 = __expf(-2.f * zc);
      float gg = (1.f - e2) / (1.f + e2);       // tanh(zc)
      float og = 1.f / (1.f + __expf(-zo));
      float cp = c_prev[off];
      float cn = fg * cp + ig * gg;
      float e2c = __expf(-2.f * cn);
      float th = (1.f - e2c) / (1.f + e2c);     // tanh(cn)
      out[off] = og * th;                        // h_new
      out[(size_t)B_DIM * H_DIM + off] = cn;     // c_new
    }
  }
}

extern "C" void kernel_launch(void* const* d_in, const int* in_sizes, int n_in,
                              void* d_out, int out_size, void* d_ws, size_t ws_size,
                              hipStream_t stream) {
  const float* x      = (const float*)d_in[0];
  const float* h_prev = (const float*)d_in[1];
  const float* c_prev = (const float*)d_in[2];
  const float* Wxi = (const float*)d_in[3];
  const float* Whi = (const float*)d_in[4];
  const float* Wxf = (const float*)d_in[5];
  const float* Whf = (const float*)d_in[6];
  const float* Wxc = (const float*)d_in[7];
  const float* Whc = (const float*)d_in[8];
  const float* Wxo = (const float*)d_in[9];
  const float* Who = (const float*)d_in[10];
  const float* bxi = (const float*)d_in[11];
  const float* bhi = (const float*)d_in[12];
  const float* bxf = (const float*)d_in[13];
  const float* bhf = (const float*)d_in[14];
  const float* bxc = (const float*)d_in[15];
  const float* bhc = (const float*)d_in[16];
  const float* bxo = (const float*)d_in[17];
  const float* bho = (const float*)d_in[18];

  unsigned short* Abf = (unsigned short*)d_ws;                                      // 32 MiB
  unsigned short* Bbf = (unsigned short*)((char*)d_ws + (size_t)B_DIM * K_DIM * 2); // +16 MiB

  pack_AB_kernel<<<2048, 256, 0, stream>>>(x, h_prev,
      Wxi, Whi, Wxf, Whf, Wxc, Whc, Wxo, Who, Abf, Bbf);
  lstm_gemm_kernel<<<512, 512, 0, stream>>>(Abf, Bbf, c_prev,
      bxi, bhi, bxf, bhf, bxc, bhc, bxo, bho, (float*)d_out);
}